// Round 7
// baseline (172.718 us; speedup 1.0000x reference)
//
#include <hip/hip_runtime.h>
#include <hip/hip_bf16.h>

#define N_NODES 50000
#define E0      800000
#define E_TOT   850000   // +N self loops

typedef short short8 __attribute__((ext_vector_type(8)));
typedef float floatx4 __attribute__((ext_vector_type(4)));

__device__ __forceinline__ float lrelu(float x) { return x > 0.f ? x : 0.2f * x; }

__device__ __forceinline__ unsigned short f2bf(float f) {   // RNE fp32->bf16
    unsigned int u = __float_as_uint(f);
    u += 0x7fffu + ((u >> 16) & 1u);
    return (unsigned short)(u >> 16);
}
__device__ __forceinline__ float lo_bf(unsigned int p) { return __uint_as_float(p << 16); }
__device__ __forceinline__ float hi_bf(unsigned int p) { return __uint_as_float(p & 0xffff0000u); }

__device__ __forceinline__ short8 pack_bf16x8(float4 a, float4 b) {
    short8 r;
    r[0] = (short)f2bf(a.x); r[1] = (short)f2bf(a.y); r[2] = (short)f2bf(a.z); r[3] = (short)f2bf(a.w);
    r[4] = (short)f2bf(b.x); r[5] = (short)f2bf(b.y); r[6] = (short)f2bf(b.z); r[7] = (short)f2bf(b.w);
    return r;
}

// w * (8 bf16 of h) accumulated into 4 float2 (hoping for v_pk_fma_f32)
__device__ __forceinline__ void fma8(float2* A, float w, uint4 h) {
    A[0].x += w * lo_bf(h.x); A[0].y += w * hi_bf(h.x);
    A[1].x += w * lo_bf(h.y); A[1].y += w * hi_bf(h.y);
    A[2].x += w * lo_bf(h.z); A[2].y += w * hi_bf(h.z);
    A[3].x += w * lo_bf(h.w); A[3].y += w * hi_bf(h.w);
}

// ---------------------------------------------------------------- init: zero deg + transpose weights to bf16
__global__ __launch_bounds__(256) void init_kernel(const float* __restrict__ W1, const float* __restrict__ W2,
                                                   unsigned short* __restrict__ Wt1, unsigned short* __restrict__ Wt2,
                                                   int* __restrict__ deg) {
    int i = blockIdx.x * 256 + threadIdx.x;
    if (i < N_NODES) deg[i] = 0;
    if (i < 128 * 128) {
        int nn = i >> 7, k = i & 127;
        Wt1[i] = f2bf(W1[k * 128 + nn]);
    } else if (i < 128 * 128 + 48 * 128) {
        int j = i - 128 * 128;
        int nn = j >> 7, k = j & 127;
        Wt2[j] = (nn < 40) ? f2bf(W2[k * 40 + nn]) : (unsigned short)0;
    }
}

// ---------------------------------------------------------------- CSR build
__global__ __launch_bounds__(256) void count_deg(const int* __restrict__ ei, int* __restrict__ deg,
                                                 int* __restrict__ rank) {
    int e = blockIdx.x * 256 + threadIdx.x;
    if (e >= E_TOT) return;
    int dst = (e < E0) ? ei[E0 + e] : (e - E0);
    rank[e] = atomicAdd(&deg[dst], 1);
}

__global__ __launch_bounds__(256) void scan_local(const int* __restrict__ deg, int* __restrict__ offs,
                                                  int* __restrict__ bsum, int n) {
    __shared__ int wsum[4];
    int t = threadIdx.x, lane = t & 63, wid = t >> 6;
    int idx = blockIdx.x * 1024 + t * 4;
    int4 v = make_int4(0, 0, 0, 0);
    if (idx < n) v = *reinterpret_cast<const int4*>(deg + idx);
    int tsum = v.x + v.y + v.z + v.w;
    int sc = tsum;
    #pragma unroll
    for (int s = 1; s < 64; s <<= 1) {
        int up = __shfl_up(sc, s);
        if (lane >= s) sc += up;
    }
    if (lane == 63) wsum[wid] = sc;
    __syncthreads();
    int woff = 0;
    for (int w = 0; w < wid; ++w) woff += wsum[w];
    int b0 = woff + (sc - tsum);
    if (idx < n) {
        int4 o;
        o.x = b0;
        o.y = b0 + v.x;
        o.z = b0 + v.x + v.y;
        o.w = b0 + v.x + v.y + v.z;
        *reinterpret_cast<int4*>(offs + idx) = o;
    }
    if (t == 255) bsum[blockIdx.x] = woff + sc;
}

// fused: each block scans bsum itself, adds its prefix; block 0 writes total
__global__ __launch_bounds__(256) void scan_addoff(int* __restrict__ offs, const int* __restrict__ bsum,
                                                   int* __restrict__ offs_total, int n, int nb) {
    __shared__ int add_sh;
    int t = threadIdx.x;
    if (t < 64) {
        int v = (t < nb) ? bsum[t] : 0;
        int sc = v;
        #pragma unroll
        for (int s = 1; s < 64; s <<= 1) {
            int up = __shfl_up(sc, s);
            if (t >= s) sc += up;
        }
        if (t == (int)blockIdx.x) add_sh = sc - v;     // exclusive prefix for this block
        if (blockIdx.x == 0 && t == nb - 1) offs_total[0] = sc;
    }
    __syncthreads();
    int idx = blockIdx.x * 1024 + t * 4;
    if (idx < n) {
        int add = add_sh;
        int4 v4 = *reinterpret_cast<int4*>(offs + idx);
        v4.x += add; v4.y += add; v4.z += add; v4.w += add;
        *reinterpret_cast<int4*>(offs + idx) = v4;
    }
}

__global__ __launch_bounds__(256) void scatter_edges(const int* __restrict__ ei, const int* __restrict__ offs,
                                                     const int* __restrict__ rank, int* __restrict__ ssrc) {
    int e = blockIdx.x * 256 + threadIdx.x;
    if (e >= E_TOT) return;
    int src, dst;
    if (e < E0) { src = ei[e]; dst = ei[E0 + e]; }
    else        { src = dst = e - E0; }
    ssrc[offs[dst] + rank[e]] = src;
}

// ---------------------------------------------------------------- GEMM1 MFMA, LDS-free (X@W1 + att dots)
__global__ __launch_bounds__(256) void gemm1_mfma(const float* __restrict__ X, const unsigned short* __restrict__ Wt,
                                                  const float* __restrict__ asw, const float* __restrict__ adw,
                                                  unsigned short* __restrict__ h1b, float* __restrict__ a_s,
                                                  float* __restrict__ a_d, int nRows) {
    int t = threadIdx.x, lane = t & 63, wave = t >> 6;
    int l15 = lane & 15, g = lane >> 4;
    int r0 = blockIdx.x * 64;
    int row = r0 + wave * 16 + l15;
    bool rv = row < nRows;
    const float* xrow = X + (size_t)(rv ? row : 0) * 128;

    float asv[8], adv[8];
    #pragma unroll
    for (int nt = 0; nt < 8; ++nt) { asv[nt] = asw[nt * 16 + l15]; adv[nt] = adw[nt * 16 + l15]; }

    floatx4 acc[8];
    #pragma unroll
    for (int nt = 0; nt < 8; ++nt) acc[nt] = (floatx4){0.f, 0.f, 0.f, 0.f};

    #pragma unroll
    for (int ks = 0; ks < 4; ++ks) {
        float4 xa = *reinterpret_cast<const float4*>(xrow + ks * 32 + g * 8);
        float4 xb = *reinterpret_cast<const float4*>(xrow + ks * 32 + g * 8 + 4);
        short8 af = pack_bf16x8(xa, xb);
        #pragma unroll
        for (int nt = 0; nt < 8; ++nt) {
            short8 bf = *reinterpret_cast<const short8*>(Wt + (size_t)(nt * 16 + l15) * 128 + ks * 32 + g * 8);
            acc[nt] = __builtin_amdgcn_mfma_f32_16x16x32_bf16(af, bf, acc[nt], 0, 0, 0);
        }
    }

    #pragma unroll
    for (int i = 0; i < 4; ++i) {
        int gr = r0 + wave * 16 + g * 4 + i;
        float s0 = 0.f, d0 = 0.f, s1 = 0.f, d1 = 0.f;
        #pragma unroll
        for (int nt = 0; nt < 4; ++nt) { s0 += acc[nt][i] * asv[nt]; d0 += acc[nt][i] * adv[nt]; }
        #pragma unroll
        for (int nt = 4; nt < 8; ++nt) { s1 += acc[nt][i] * asv[nt]; d1 += acc[nt][i] * adv[nt]; }
        #pragma unroll
        for (int sh = 1; sh < 16; sh <<= 1) {
            s0 += __shfl_xor(s0, sh); d0 += __shfl_xor(d0, sh);
            s1 += __shfl_xor(s1, sh); d1 += __shfl_xor(d1, sh);
        }
        if (gr < nRows) {
            if (l15 == 0) {
                a_s[gr * 2] = s0;     a_d[gr * 2] = d0;
                a_s[gr * 2 + 1] = s1; a_d[gr * 2 + 1] = d1;
            }
            #pragma unroll
            for (int nt = 0; nt < 8; ++nt)
                h1b[(size_t)gr * 128 + nt * 16 + l15] = f2bf(acc[nt][i]);
        }
    }
}

// ---------------------------------------------------------------- GEMM2 MFMA, LDS-free (X2@W2 + att dots), N=40 (pad 48)
__global__ __launch_bounds__(256) void gemm2_mfma(const float* __restrict__ X, const unsigned short* __restrict__ Wt,
                                                  const float* __restrict__ asw, const float* __restrict__ adw,
                                                  unsigned short* __restrict__ h2b, float* __restrict__ a_s,
                                                  float* __restrict__ a_d, int nRows) {
    int t = threadIdx.x, lane = t & 63, wave = t >> 6;
    int l15 = lane & 15, g = lane >> 4;
    int r0 = blockIdx.x * 64;
    int row = r0 + wave * 16 + l15;
    bool rv = row < nRows;
    const float* xrow = X + (size_t)(rv ? row : 0) * 128;

    float asv[3], adv[3];
    #pragma unroll
    for (int nt = 0; nt < 3; ++nt) {
        int col = nt * 16 + l15;
        asv[nt] = (col < 40) ? asw[col] : 0.f;
        adv[nt] = (col < 40) ? adw[col] : 0.f;
    }

    floatx4 acc[3];
    #pragma unroll
    for (int nt = 0; nt < 3; ++nt) acc[nt] = (floatx4){0.f, 0.f, 0.f, 0.f};

    #pragma unroll
    for (int ks = 0; ks < 4; ++ks) {
        float4 xa = *reinterpret_cast<const float4*>(xrow + ks * 32 + g * 8);
        float4 xb = *reinterpret_cast<const float4*>(xrow + ks * 32 + g * 8 + 4);
        short8 af = pack_bf16x8(xa, xb);
        #pragma unroll
        for (int nt = 0; nt < 3; ++nt) {
            short8 bf = *reinterpret_cast<const short8*>(Wt + (size_t)(nt * 16 + l15) * 128 + ks * 32 + g * 8);
            acc[nt] = __builtin_amdgcn_mfma_f32_16x16x32_bf16(af, bf, acc[nt], 0, 0, 0);
        }
    }

    #pragma unroll
    for (int i = 0; i < 4; ++i) {
        int gr = r0 + wave * 16 + g * 4 + i;
        float ps = 0.f, pd = 0.f;
        #pragma unroll
        for (int nt = 0; nt < 3; ++nt) { ps += acc[nt][i] * asv[nt]; pd += acc[nt][i] * adv[nt]; }
        #pragma unroll
        for (int sh = 1; sh < 16; sh <<= 1) { ps += __shfl_xor(ps, sh); pd += __shfl_xor(pd, sh); }
        if (gr < nRows) {
            if (l15 == 0) { a_s[gr] = ps; a_d[gr] = pd; }
            #pragma unroll
            for (int nt = 0; nt < 3; ++nt) {
                int col = nt * 16 + l15;
                if (col < 40) h2b[(size_t)gr * 40 + col] = f2bf(acc[nt][i]);
            }
        }
    }
}

// ---------------------------------------------------------------- aggregation layer1 (+bias+ELU)
// wave/node; c=lane&15 (ch c*8..+7), q=lane>>4 (slot); j-step 32 => 8 uint4 gathers in flight
__global__ __launch_bounds__(256) void aggregate1(const unsigned short* __restrict__ Hb, const float* __restrict__ as,
                                                  const float* __restrict__ ad, const int* __restrict__ offs,
                                                  const int* __restrict__ ssrc, const float* __restrict__ bias,
                                                  float* __restrict__ Xout, int n) {
    __shared__ int   sbuf[4][64];
    __shared__ float wbuf[4][2][64];
    int t = threadIdx.x, lane = t & 63, wid = t >> 6;
    int node = blockIdx.x * 4 + wid;
    if (node >= n) return;
    int c = lane & 15, q = lane >> 4, head = c >> 3;
    int beg = offs[node], end = offs[node + 1];
    float ad0 = ad[node * 2], ad1 = ad[node * 2 + 1];
    float den0 = 0.f, den1 = 0.f;
    float2 acc0[4], acc1[4];
    #pragma unroll
    for (int m = 0; m < 4; ++m) { acc0[m] = make_float2(0.f, 0.f); acc1[m] = make_float2(0.f, 0.f); }

    for (int i0 = beg; i0 < end; i0 += 64) {
        int cnt = min(64, end - i0);
        int s = 0; float w0 = 0.f, w1 = 0.f;
        if (lane < cnt) {
            s = ssrc[i0 + lane];
            float2 av = *reinterpret_cast<const float2*>(&as[s * 2]);
            w0 = __expf(lrelu(av.x + ad0));
            w1 = __expf(lrelu(av.y + ad1));
        }
        sbuf[wid][lane]    = s;
        wbuf[wid][0][lane] = w0;
        wbuf[wid][1][lane] = w1;
        den0 += w0; den1 += w1;
        for (int j = 0; j < cnt; j += 32) {
            int sE[8]; float wE[8];
            #pragma unroll
            for (int k = 0; k < 8; ++k) {
                int e = j + q + 4 * k;
                sE[k] = sbuf[wid][e];
                wE[k] = wbuf[wid][head][e];
            }
            uint4 hE[8];
            #pragma unroll
            for (int k = 0; k < 8; ++k)
                hE[k] = *reinterpret_cast<const uint4*>(&Hb[(size_t)sE[k] * 128 + c * 8]);
            #pragma unroll
            for (int k = 0; k < 8; ++k)
                fma8((k & 1) ? acc1 : acc0, wE[k], hE[k]);
        }
    }
    #pragma unroll
    for (int m = 0; m < 4; ++m) { acc0[m].x += acc1[m].x; acc0[m].y += acc1[m].y; }
    #pragma unroll
    for (int sh = 32; sh > 0; sh >>= 1) { den0 += __shfl_xor(den0, sh); den1 += __shfl_xor(den1, sh); }
    #pragma unroll
    for (int m = 0; m < 4; ++m) {
        acc0[m].x += __shfl_xor(acc0[m].x, 16); acc0[m].x += __shfl_xor(acc0[m].x, 32);
        acc0[m].y += __shfl_xor(acc0[m].y, 16); acc0[m].y += __shfl_xor(acc0[m].y, 32);
    }
    if (q == 0) {
        float den = (head ? den1 : den0) + 1e-16f;
        float4 b0 = *reinterpret_cast<const float4*>(&bias[c * 8]);
        float4 b1 = *reinterpret_cast<const float4*>(&bias[c * 8 + 4]);
        float va[8] = {acc0[0].x, acc0[0].y, acc0[1].x, acc0[1].y, acc0[2].x, acc0[2].y, acc0[3].x, acc0[3].y};
        float bb[8] = {b0.x, b0.y, b0.z, b0.w, b1.x, b1.y, b1.z, b1.w};
        float o[8];
        #pragma unroll
        for (int k = 0; k < 8; ++k) {
            float v = va[k] / den + bb[k];
            o[k] = v > 0.f ? v : (__expf(v) - 1.f);   // ELU
        }
        *reinterpret_cast<float4*>(&Xout[(size_t)node * 128 + c * 8])     = make_float4(o[0], o[1], o[2], o[3]);
        *reinterpret_cast<float4*>(&Xout[(size_t)node * 128 + c * 8 + 4]) = make_float4(o[4], o[5], o[6], o[7]);
    }
}

// ---------------------------------------------------------------- aggregation layer2 (+bias) -> out
// wave/node; 12 groups x 5 lanes x uint4 (8 ch); j-step 24; lanes 60-63 dead
__global__ __launch_bounds__(256) void aggregate2(const unsigned short* __restrict__ Hb, const float* __restrict__ as,
                                                  const float* __restrict__ ad, const int* __restrict__ offs,
                                                  const int* __restrict__ ssrc, const float* __restrict__ bias,
                                                  float* __restrict__ out, int n) {
    __shared__ int   sbuf[4][76];
    __shared__ float wbuf[4][76];
    int t = threadIdx.x, lane = t & 63, wid = t >> 6;
    int node = blockIdx.x * 4 + wid;
    if (node >= n) return;
    int g = lane / 5, c = lane % 5;
    bool dead = (g >= 12);
    if (lane < 12) { sbuf[wid][64 + lane] = 0; wbuf[wid][64 + lane] = 0.f; }   // zero pad slots 64..75
    int beg = offs[node], end = offs[node + 1];
    float adv = ad[node];
    float den = 0.f;
    float2 acc0[4], acc1[4];
    #pragma unroll
    for (int m = 0; m < 4; ++m) { acc0[m] = make_float2(0.f, 0.f); acc1[m] = make_float2(0.f, 0.f); }

    for (int i0 = beg; i0 < end; i0 += 64) {
        int cnt = min(64, end - i0);
        int s = 0; float w = 0.f;
        if (lane < cnt) {
            s = ssrc[i0 + lane];
            w = __expf(lrelu(as[s] + adv));
        }
        sbuf[wid][lane] = s;
        wbuf[wid][lane] = w;
        den += w;
        for (int j = 0; j < cnt; j += 24) {
            int e0 = dead ? 64 : (j + g);
            int e1 = dead ? 64 : (j + 12 + g);
            int   s0 = sbuf[wid][e0], s1 = sbuf[wid][e1];
            float w0 = wbuf[wid][e0], w1 = wbuf[wid][e1];
            uint4 h0 = *reinterpret_cast<const uint4*>(&Hb[(size_t)s0 * 40 + c * 8]);
            uint4 h1 = *reinterpret_cast<const uint4*>(&Hb[(size_t)s1 * 40 + c * 8]);
            fma8(acc0, w0, h0);
            fma8(acc1, w1, h1);
        }
    }
    #pragma unroll
    for (int m = 0; m < 4; ++m) { acc0[m].x += acc1[m].x; acc0[m].y += acc1[m].y; }
    #pragma unroll
    for (int sh = 32; sh > 0; sh >>= 1) den += __shfl_xor(den, sh);
    // merge 12 groups (stride-5 lanes): +30, +15, then +5,+10 ; lanes 0..4 hold result
    #pragma unroll
    for (int m = 0; m < 4; ++m) {
        float ax = acc0[m].x, ay = acc0[m].y;
        ax += __shfl(ax, lane + 30); ay += __shfl(ay, lane + 30);
        ax += __shfl(ax, lane + 15); ay += __shfl(ay, lane + 15);
        float ax5 = __shfl(ax, lane + 5),  ay5 = __shfl(ay, lane + 5);
        float ax10 = __shfl(ax, lane + 10), ay10 = __shfl(ay, lane + 10);
        acc0[m].x = ax + ax5 + ax10;
        acc0[m].y = ay + ay5 + ay10;
    }
    if (lane < 5) {
        float dinv = 1.f / (den + 1e-16f);
        float4 b0 = *reinterpret_cast<const float4*>(&bias[c * 8]);
        float4 b1 = *reinterpret_cast<const float4*>(&bias[c * 8 + 4]);
        float4 o0, o1;
        o0.x = acc0[0].x * dinv + b0.x; o0.y = acc0[0].y * dinv + b0.y;
        o0.z = acc0[1].x * dinv + b0.z; o0.w = acc0[1].y * dinv + b0.w;
        o1.x = acc0[2].x * dinv + b1.x; o1.y = acc0[2].y * dinv + b1.y;
        o1.z = acc0[3].x * dinv + b1.z; o1.w = acc0[3].y * dinv + b1.w;
        *reinterpret_cast<float4*>(&out[(size_t)node * 40 + c * 8])     = o0;
        *reinterpret_cast<float4*>(&out[(size_t)node * 40 + c * 8 + 4]) = o1;
    }
}

// ---------------------------------------------------------------- launch
extern "C" void kernel_launch(void* const* d_in, const int* in_sizes, int n_in,
                              void* d_out, int out_size, void* d_ws, size_t ws_size,
                              hipStream_t stream) {
    (void)in_sizes; (void)n_in; (void)out_size; (void)ws_size;
    const float* x    = (const float*)d_in[0];
    const int*   ei   = (const int*)d_in[1];
    const float* W1   = (const float*)d_in[2];
    const float* as1w = (const float*)d_in[3];
    const float* ad1w = (const float*)d_in[4];
    const float* b1   = (const float*)d_in[5];
    const float* W2   = (const float*)d_in[6];
    const float* as2w = (const float*)d_in[7];
    const float* ad2w = (const float*)d_in[8];
    const float* b2   = (const float*)d_in[9];
    float* out = (float*)d_out;

    float* ws = (float*)d_ws;
    float* h1slot = ws; ws += (size_t)N_NODES * 128;
    float* x2     = ws; ws += (size_t)N_NODES * 128;
    float* a_s1 = ws; ws += N_NODES * 2;
    float* a_d1 = ws; ws += N_NODES * 2;
    float* a_s2 = ws; ws += N_NODES;
    float* a_d2 = ws; ws += N_NODES;
    float* h2slot = ws; ws += (size_t)N_NODES * 40;
    int* offs = (int*)ws;
    int* deg  = offs + 50004;
    int* ssrc = deg + N_NODES;
    int* bsum = ssrc + E_TOT;                         // 64 ints
    unsigned short* Wt1 = (unsigned short*)(bsum + 64);
    unsigned short* Wt2 = Wt1 + 128 * 128;

    unsigned short* h1b = (unsigned short*)h1slot;
    unsigned short* h2b = (unsigned short*)h2slot;
    int* rank = (int*)x2;    // dead after scatter_edges; x2 written later by aggregate1

    const int NB = (N_NODES + 1023) / 1024;           // 49

    init_kernel<<<196, 256, 0, stream>>>(W1, W2, Wt1, Wt2, deg);
    count_deg<<<(E_TOT + 255) / 256, 256, 0, stream>>>(ei, deg, rank);
    scan_local<<<NB, 256, 0, stream>>>(deg, offs, bsum, N_NODES);
    scan_addoff<<<NB, 256, 0, stream>>>(offs, bsum, offs + N_NODES, N_NODES, NB);
    scatter_edges<<<(E_TOT + 255) / 256, 256, 0, stream>>>(ei, offs, rank, ssrc);

    gemm1_mfma<<<(N_NODES + 63) / 64, 256, 0, stream>>>(x, Wt1, as1w, ad1w, h1b, a_s1, a_d1, N_NODES);
    aggregate1<<<(N_NODES + 3) / 4, 256, 0, stream>>>(h1b, a_s1, a_d1, offs, ssrc, b1, x2, N_NODES);
    gemm2_mfma<<<(N_NODES + 63) / 64, 256, 0, stream>>>(x2, Wt2, as2w, ad2w, h2b, a_s2, a_d2, N_NODES);
    aggregate2<<<(N_NODES + 3) / 4, 256, 0, stream>>>(h2b, a_s2, a_d2, offs, ssrc, b2, out, N_NODES);
}